// Round 1
// baseline (4587.024 us; speedup 1.0000x reference)
//
#include <hip/hip_runtime.h>

// NNConv: N=25000 nodes, E=400000 edges, NIN=NOUT=32, HID=128
// out[n,o] = bias[o] + sum_i x[n,i]*root[i,o]
//          + sum_{e: dst[e]=n} sum_i x[src[e],i] * W[e,i,o]
// W[e,i,o] = sum_k h[e,k]*w2[k, i*32+o] + b2[i*32+o]
// h[e,k]   = relu(sum_i ea[e,i]*w1[i,k] + b1[k])

#define NN    25000
#define EE    400000
#define NIN_  32
#define NOUT_ 32
#define HID_  128
#define ET    64   // edges per block
#define KC    4    // k-chunk staged in LDS

// ---------------- kernel 1: out = x @ root + bias ----------------
__global__ __launch_bounds__(256) void root_kernel(
    const float* __restrict__ x, const float* __restrict__ root,
    const float* __restrict__ bias, float* __restrict__ out)
{
    int gid = blockIdx.x * 256 + threadIdx.x;   // exactly NN*32 threads
    int n = gid >> 5, o = gid & 31;
    float acc = bias[o];
    const float* xr = x + (n << 5);
#pragma unroll
    for (int i = 0; i < 32; ++i)
        acc = fmaf(xr[i], root[(i << 5) + o], acc);
    out[gid] = acc;
}

// ---------------- kernel 2: fused edge MLP + einsum + scatter ----------------
__global__ __launch_bounds__(256) void edge_kernel(
    const float* __restrict__ x,
    const int*   __restrict__ ei,     // [2,E] int32: src then dst
    const float* __restrict__ ea,     // [E,32]
    const float* __restrict__ w1,     // [32,128]
    const float* __restrict__ b1,     // [128]
    const float* __restrict__ w2,     // [128,1024]
    const float* __restrict__ b2,     // [1024]
    float* __restrict__ out)          // [N,32], pre-initialized by root_kernel
{
    __shared__ float bufL[ET][NIN_ + 1];   // 8.4 KB: edge_attr, then x[src] (padded +1: conflict-free)
    __shared__ float hLT[HID_][ET];        // 32 KB: h transposed -> main-loop reads conflict-free
    __shared__ float w2L[KC][1024];        // 16 KB staged w2 rows
    __shared__ int   srcL[ET];
    __shared__ int   dstL[ET];

    const int t   = threadIdx.x;
    const int eg0 = blockIdx.x * ET;

    if (t < ET)            srcL[t]      = ei[eg0 + t];
    else if (t < 2 * ET)   dstL[t - ET] = ei[EE + eg0 + (t - ET)];

    // stage edge_attr (coalesced scalar loads into padded LDS)
    {
        const float* eap = ea + eg0 * NIN_;
#pragma unroll
        for (int j = 0; j < 8; ++j) {
            int f = t + j * 256;
            bufL[f >> 5][f & 31] = eap[f];
        }
    }
    __syncthreads();

    // phase 1: h = relu(ea @ w1 + b1) -> hLT[k][e]
    {
        const int e  = t >> 2;           // 0..63
        const int kb = (t & 3) << 5;     // 0,32,64,96
        float ear[32];
#pragma unroll
        for (int i = 0; i < 32; ++i) ear[i] = bufL[e][i];  // broadcast, conflict-free
        for (int q = 0; q < 8; ++q) {
            const int k = kb + (q << 2);
            float4 g = {0.f, 0.f, 0.f, 0.f};
#pragma unroll
            for (int i = 0; i < 32; ++i) {
                float4 wv = *(const float4*)(w1 + i * HID_ + k);  // L1-cached (16 KB)
                g.x = fmaf(ear[i], wv.x, g.x);
                g.y = fmaf(ear[i], wv.y, g.y);
                g.z = fmaf(ear[i], wv.z, g.z);
                g.w = fmaf(ear[i], wv.w, g.w);
            }
            float4 bv = *(const float4*)(b1 + k);
            hLT[k + 0][e] = fmaxf(g.x + bv.x, 0.f);
            hLT[k + 1][e] = fmaxf(g.y + bv.y, 0.f);
            hLT[k + 2][e] = fmaxf(g.z + bv.z, 0.f);
            hLT[k + 3][e] = fmaxf(g.w + bv.w, 0.f);
        }
    }
    __syncthreads();

    // phase 2: overwrite bufL with gathered x[src[e]]
#pragma unroll
    for (int j = 0; j < 8; ++j) {
        int f = t + j * 256;
        int e = f >> 5, i = f & 31;
        bufL[e][i] = x[srcL[e] * NIN_ + i];
    }
    __syncthreads();

    // main contraction: thread owns edges {e0,e1} x 4 contiguous outputs
    const int ep = t & 31;
    const int ob = (t >> 5) << 2;       // output base 0..28
    const int e0 = ep, e1 = ep + 32;
    float xs0[32], xs1[32];
#pragma unroll
    for (int i = 0; i < 32; ++i) { xs0[i] = bufL[e0][i]; xs1[i] = bufL[e1][i]; }

    float acc0[4] = {0.f,0.f,0.f,0.f}, acc1[4] = {0.f,0.f,0.f,0.f};

    for (int kc = 0; kc < HID_ / KC; ++kc) {
        __syncthreads();                       // w2L safe to overwrite
        {
            const float4* w2p = (const float4*)(w2 + kc * (KC * 1024));
            float4*       w2d = (float4*)w2L;
#pragma unroll
            for (int j = 0; j < 4; ++j)
                w2d[t + j * 256] = w2p[t + j * 256];   // coalesced dwordx4
        }
        __syncthreads();
        for (int k = 0; k < KC; ++k) {
            float g0[4] = {0.f,0.f,0.f,0.f}, g1[4] = {0.f,0.f,0.f,0.f};
#pragma unroll
            for (int i = 0; i < 32; ++i) {
                float4 wv = *(const float4*)&w2L[k][(i << 5) + ob];  // ds_read_b128, 2 addrs/wave
                g0[0] = fmaf(xs0[i], wv.x, g0[0]);
                g0[1] = fmaf(xs0[i], wv.y, g0[1]);
                g0[2] = fmaf(xs0[i], wv.z, g0[2]);
                g0[3] = fmaf(xs0[i], wv.w, g0[3]);
                g1[0] = fmaf(xs1[i], wv.x, g1[0]);
                g1[1] = fmaf(xs1[i], wv.y, g1[1]);
                g1[2] = fmaf(xs1[i], wv.z, g1[2]);
                g1[3] = fmaf(xs1[i], wv.w, g1[3]);
            }
            const int kk = kc * KC + k;
            const float h0 = hLT[kk][e0], h1 = hLT[kk][e1];  // conflict-free
#pragma unroll
            for (int j = 0; j < 4; ++j) {
                acc0[j] = fmaf(h0, g0[j], acc0[j]);
                acc1[j] = fmaf(h1, g1[j], acc1[j]);
            }
        }
    }

    // b2 contribution: msg += xs @ b2(reshaped 32x32)
#pragma unroll
    for (int i = 0; i < 32; ++i) {
        float4 bv = *(const float4*)(b2 + (i << 5) + ob);
        acc0[0] = fmaf(xs0[i], bv.x, acc0[0]);
        acc0[1] = fmaf(xs0[i], bv.y, acc0[1]);
        acc0[2] = fmaf(xs0[i], bv.z, acc0[2]);
        acc0[3] = fmaf(xs0[i], bv.w, acc0[3]);
        acc1[0] = fmaf(xs1[i], bv.x, acc1[0]);
        acc1[1] = fmaf(xs1[i], bv.y, acc1[1]);
        acc1[2] = fmaf(xs1[i], bv.z, acc1[2]);
        acc1[3] = fmaf(xs1[i], bv.w, acc1[3]);
    }

    // scatter-add to destination nodes
    const int d0 = dstL[e0], d1 = dstL[e1];
#pragma unroll
    for (int j = 0; j < 4; ++j) {
        atomicAdd(&out[d0 * NOUT_ + ob + j], acc0[j]);
        atomicAdd(&out[d1 * NOUT_ + ob + j], acc1[j]);
    }
}

extern "C" void kernel_launch(void* const* d_in, const int* in_sizes, int n_in,
                              void* d_out, int out_size, void* d_ws, size_t ws_size,
                              hipStream_t stream) {
    const float* x    = (const float*)d_in[0];
    const int*   ei   = (const int*)  d_in[1];
    const float* ea   = (const float*)d_in[2];
    const float* w1   = (const float*)d_in[3];
    const float* b1   = (const float*)d_in[4];
    const float* w2   = (const float*)d_in[5];
    const float* b2   = (const float*)d_in[6];
    const float* root = (const float*)d_in[7];
    const float* bias = (const float*)d_in[8];
    float* out = (float*)d_out;

    // out = x @ root + bias  (exactly NN*32 threads)
    root_kernel<<<(NN * NOUT_) / 256, 256, 0, stream>>>(x, root, bias, out);
    // fused edge pipeline + atomic scatter (E/ET blocks, exact)
    edge_kernel<<<EE / ET, 256, 0, stream>>>(x, ei, ea, w1, b1, w2, b2, out);
}

// Round 2
// 411.969 us; speedup vs baseline: 11.1344x; 11.1344x over previous
//
#include <hip/hip_runtime.h>

// NNConv on MI355X. Dominant contraction recast as bf16 MFMA GEMM:
//   msg[E x 32] = Z[E x 4096] @ w2r[4096 x 32],  Z[e, c*32+i] = h[e,c]*xs[e,i]
// Z generated on-the-fly per A-fragment (8 muls + bf16 cvt), never materialized.
// Phase-1 h = relu(ea@w1+b1) also via MFMA, hT wave-private in LDS.
// w1/w2/b2 pre-packed to bf16 MFMA B/A fragment layout in d_ws.

#define NN    25000
#define EE    400000

typedef __bf16 bf16x8 __attribute__((ext_vector_type(8)));
typedef float  f32x16 __attribute__((ext_vector_type(16)));

// ---------------- pack: w2/w1/b2 -> bf16 fragment layouts in ws ----------------
// w2p[c][ih][lane][j] = w2[c, (ih*16 + (lane>>5)*8 + j)*32 + (lane&31)]   (131072)
// w1p[r][kk][lane][j] = w1[(kk*16 + (lane>>5)*8 + j)*128 + r*32 + (lane&31)] (4096)
// b2p[ih][lane][j]    = b2[(ih*16 + (lane>>5)*8 + j)*32 + (lane&31)]      (1024)
__global__ __launch_bounds__(256) void pack_kernel(
    const float* __restrict__ w1, const float* __restrict__ w2,
    const float* __restrict__ b2,
    __bf16* __restrict__ w2p, __bf16* __restrict__ w1p, __bf16* __restrict__ b2p)
{
    int t = blockIdx.x * 256 + threadIdx.x;   // exactly 136192 threads
    if (t < 131072) {
        int j = t & 7, lane = (t >> 3) & 63, ih = (t >> 9) & 1, c = t >> 10;
        w2p[t] = (__bf16)w2[c * 1024 + (ih * 16 + ((lane >> 5) << 3) + j) * 32 + (lane & 31)];
    } else if (t < 135168) {
        int u = t - 131072;
        int j = u & 7, lane = (u >> 3) & 63, kk = (u >> 9) & 1, r = u >> 10;
        w1p[u] = (__bf16)w1[(kk * 16 + ((lane >> 5) << 3) + j) * 128 + r * 32 + (lane & 31)];
    } else {
        int u = t - 135168;
        int j = u & 7, lane = (u >> 3) & 63, ih = u >> 9;
        b2p[u] = (__bf16)b2[(ih * 16 + ((lane >> 5) << 3) + j) * 32 + (lane & 31)];
    }
}

// ---------------- out = x @ root + bias (fp32, trivial) ----------------
__global__ __launch_bounds__(256) void root_kernel(
    const float* __restrict__ x, const float* __restrict__ root,
    const float* __restrict__ bias, float* __restrict__ out)
{
    int gid = blockIdx.x * 256 + threadIdx.x;   // exactly NN*32
    int n = gid >> 5, o = gid & 31;
    float acc = bias[o];
    const float* xr = x + (n << 5);
#pragma unroll
    for (int i = 0; i < 32; ++i)
        acc = fmaf(xr[i], root[(i << 5) + o], acc);
    out[gid] = acc;
}

// ---------------- fused MFMA edge kernel ----------------
// 256 thr = 4 waves, 32 edges/wave, 128 edges/block, 3125 blocks.
__global__ __launch_bounds__(256) void edge_kernel(
    const float*  __restrict__ x,
    const int*    __restrict__ ei,
    const float*  __restrict__ ea,
    const float*  __restrict__ b1,
    const __bf16* __restrict__ w2p,
    const __bf16* __restrict__ w1p,
    const __bf16* __restrict__ b2p,
    float* __restrict__ out)
{
    __shared__ __bf16 hT[4][128][32];     // 32 KB, wave-private slices
    __shared__ __bf16 w2c[16 * 2 * 512];  // 32 KB K-chunk of packed w2

    const int t    = threadIdx.x;
    const int w    = t >> 6;
    const int lane = t & 63;
    const int l    = lane & 31;
    const int half = lane >> 5;
    const int eb   = blockIdx.x * 128 + w * 32;
    const int e    = eb + l;

    // ---- phase 1: hT[w][c][e] = relu(ea@w1+b1) via 8 MFMAs, wave-private ----
    {
        bf16x8 eaf[2];
#pragma unroll
        for (int kk = 0; kk < 2; ++kk) {
            float4 a0 = *(const float4*)(ea + e * 32 + kk * 16 + half * 8);
            float4 a1 = *(const float4*)(ea + e * 32 + kk * 16 + half * 8 + 4);
            eaf[kk][0] = (__bf16)a0.x; eaf[kk][1] = (__bf16)a0.y;
            eaf[kk][2] = (__bf16)a0.z; eaf[kk][3] = (__bf16)a0.w;
            eaf[kk][4] = (__bf16)a1.x; eaf[kk][5] = (__bf16)a1.y;
            eaf[kk][6] = (__bf16)a1.z; eaf[kk][7] = (__bf16)a1.w;
        }
#pragma unroll
        for (int r = 0; r < 4; ++r) {
            bf16x8 w1f0 = *(const bf16x8*)(w1p + ((r * 2 + 0) * 64 + lane) * 8);
            bf16x8 w1f1 = *(const bf16x8*)(w1p + ((r * 2 + 1) * 64 + lane) * 8);
            f32x16 hacc;
#pragma unroll
            for (int i = 0; i < 16; ++i) hacc[i] = 0.f;
            hacc = __builtin_amdgcn_mfma_f32_32x32x16_bf16(w1f0, eaf[0], hacc, 0, 0, 0);
            hacc = __builtin_amdgcn_mfma_f32_32x32x16_bf16(w1f1, eaf[1], hacc, 0, 0, 0);
#pragma unroll
            for (int i = 0; i < 16; ++i) {
                int row = (i & 3) + ((i >> 2) << 3) + (half << 2);   // verified C/D map
                int c   = r * 32 + row;
                hT[w][c][l] = (__bf16)fmaxf(hacc[i] + b1[c], 0.f);
            }
        }
    }

    // ---- gather xs = x[src[e]] : per-lane 16 floats at i = ih*16 + half*8 + j ----
    const int srcv = ei[e];
    float xsv[16];
#pragma unroll
    for (int ih = 0; ih < 2; ++ih) {
        float4 a0 = *(const float4*)(x + srcv * 32 + ih * 16 + half * 8);
        float4 a1 = *(const float4*)(x + srcv * 32 + ih * 16 + half * 8 + 4);
        xsv[ih * 8 + 0] = a0.x; xsv[ih * 8 + 1] = a0.y;
        xsv[ih * 8 + 2] = a0.z; xsv[ih * 8 + 3] = a0.w;
        xsv[ih * 8 + 4] = a1.x; xsv[ih * 8 + 5] = a1.y;
        xsv[ih * 8 + 6] = a1.z; xsv[ih * 8 + 7] = a1.w;
    }

    f32x16 acc;
#pragma unroll
    for (int i = 0; i < 16; ++i) acc[i] = 0.f;

    // ---- main K loop: 8 chunks x 16 c, register-prefetched w2 chunk staging ----
    const char* w2g = (const char*)w2p;
    float4 pf[8];
#pragma unroll
    for (int s = 0; s < 8; ++s)
        pf[s] = *(const float4*)(w2g + t * 16 + s * 4096);

    for (int cc = 0; cc < 8; ++cc) {
        __syncthreads();                      // prev chunk's compute done
#pragma unroll
        for (int s = 0; s < 8; ++s)
            ((float4*)w2c)[t + s * 256] = pf[s];
        __syncthreads();
        if (cc < 7) {
#pragma unroll
            for (int s = 0; s < 8; ++s)       // overlap next chunk load with compute
                pf[s] = *(const float4*)(w2g + (cc + 1) * 32768 + t * 16 + s * 4096);
        }
#pragma unroll
        for (int cl = 0; cl < 16; ++cl) {
            const int   c  = cc * 16 + cl;
            const float hv = (float)hT[w][c][l];
#pragma unroll
            for (int ih = 0; ih < 2; ++ih) {
                bf16x8 bfr = *(const bf16x8*)&w2c[(cl * 2 + ih) * 512 + lane * 8];
                bf16x8 afr;
#pragma unroll
                for (int j = 0; j < 8; ++j)
                    afr[j] = (__bf16)(hv * xsv[ih * 8 + j]);   // Z row on the fly
                acc = __builtin_amdgcn_mfma_f32_32x32x16_bf16(afr, bfr, acc, 0, 0, 0);
            }
        }
    }

    // ---- b2 contribution: one extra K-step with h == 1 ----
#pragma unroll
    for (int ih = 0; ih < 2; ++ih) {
        bf16x8 bfr = *(const bf16x8*)(b2p + (ih * 64 + lane) * 8);
        bf16x8 afr;
#pragma unroll
        for (int j = 0; j < 8; ++j)
            afr[j] = (__bf16)xsv[ih * 8 + j];
        acc = __builtin_amdgcn_mfma_f32_32x32x16_bf16(afr, bfr, acc, 0, 0, 0);
    }

    // ---- scatter: D col = output o = lane&31, row = edge via C/D map ----
#pragma unroll
    for (int i = 0; i < 16; ++i) {
        int el = (i & 3) + ((i >> 2) << 3) + (half << 2);
        int d  = ei[EE + eb + el];            // broadcast load, L2-hot
        atomicAdd(out + d * 32 + l, acc[i]);
    }
}

extern "C" void kernel_launch(void* const* d_in, const int* in_sizes, int n_in,
                              void* d_out, int out_size, void* d_ws, size_t ws_size,
                              hipStream_t stream) {
    const float* x    = (const float*)d_in[0];
    const int*   ei   = (const int*)  d_in[1];
    const float* ea   = (const float*)d_in[2];
    const float* w1   = (const float*)d_in[3];
    const float* b1   = (const float*)d_in[4];
    const float* w2   = (const float*)d_in[5];
    const float* b2   = (const float*)d_in[6];
    const float* root = (const float*)d_in[7];
    const float* bias = (const float*)d_in[8];
    float* out = (float*)d_out;

    __bf16* w2p = (__bf16*)d_ws;                          // 262144 B
    __bf16* w1p = (__bf16*)((char*)d_ws + 262144);        //   8192 B
    __bf16* b2p = (__bf16*)((char*)d_ws + 270336);        //   2048 B

    pack_kernel<<<532, 256, 0, stream>>>(w1, w2, b2, w2p, w1p, b2p);
    root_kernel<<<(NN * 32) / 256, 256, 0, stream>>>(x, root, bias, out);
    edge_kernel<<<EE / 128, 256, 0, stream>>>(x, ei, ea, b1, w2p, w1p, b2p, out);
}

// Round 3
// 405.345 us; speedup vs baseline: 11.3163x; 1.0163x over previous
//
#include <hip/hip_runtime.h>
#include <hip/hip_bf16.h>

// NNConv on MI355X. Dominant contraction as bf16 MFMA GEMM:
//   msg[E x 32] = Z[E x 4096] @ w2r[4096 x 32],  Z[e, c*32+i] = h[e,c]*xs[e,i]
// Z generated on-the-fly per A-fragment, never materialized.
// Round 3: 8x-replicated accumulators in ws (XCD-local atomics via blockIdx%8),
// 16 KB w2 chunks (LDS 48 KB -> 3 blocks/CU), packed bf16 converts.

#define NN    25000
#define EE    400000

typedef __bf16 bf16x8 __attribute__((ext_vector_type(8)));
typedef float  f32x16 __attribute__((ext_vector_type(16)));

// ---------------- pack: w2/w1/b2 -> bf16 fragment layouts in ws ----------------
__global__ __launch_bounds__(256) void pack_kernel(
    const float* __restrict__ w1, const float* __restrict__ w2,
    const float* __restrict__ b2,
    __bf16* __restrict__ w2p, __bf16* __restrict__ w1p, __bf16* __restrict__ b2p)
{
    int t = blockIdx.x * 256 + threadIdx.x;   // exactly 136192 threads
    if (t < 131072) {
        int j = t & 7, lane = (t >> 3) & 63, ih = (t >> 9) & 1, c = t >> 10;
        w2p[t] = (__bf16)w2[c * 1024 + (ih * 16 + ((lane >> 5) << 3) + j) * 32 + (lane & 31)];
    } else if (t < 135168) {
        int u = t - 131072;
        int j = u & 7, lane = (u >> 3) & 63, kk = (u >> 9) & 1, r = u >> 10;
        w1p[u] = (__bf16)w1[(kk * 16 + ((lane >> 5) << 3) + j) * 128 + r * 32 + (lane & 31)];
    } else {
        int u = t - 135168;
        int j = u & 7, lane = (u >> 3) & 63, ih = u >> 9;
        b2p[u] = (__bf16)b2[(ih * 16 + ((lane >> 5) << 3) + j) * 32 + (lane & 31)];
    }
}

// ---------------- out = x @ root + bias (fp32, trivial) ----------------
__global__ __launch_bounds__(256) void root_kernel(
    const float* __restrict__ x, const float* __restrict__ root,
    const float* __restrict__ bias, float* __restrict__ out)
{
    int gid = blockIdx.x * 256 + threadIdx.x;   // exactly NN*32
    int n = gid >> 5, o = gid & 31;
    float acc = bias[o];
    const float* xr = x + (n << 5);
#pragma unroll
    for (int i = 0; i < 32; ++i)
        acc = fmaf(xr[i], root[(i << 5) + o], acc);
    out[gid] = acc;
}

// ---------------- out += sum of replicas ----------------
__global__ __launch_bounds__(256) void reduce_kernel(
    const float* __restrict__ part, int ncopies, float* __restrict__ out)
{
    int g = blockIdx.x * 256 + threadIdx.x;   // exactly NN*32
    float s = out[g];
    for (int c = 0; c < ncopies; ++c) s += part[(size_t)c * 800000 + g];
    out[g] = s;
}

// ---------------- fused MFMA edge kernel ----------------
// 256 thr = 4 waves, 32 edges/wave, 128 edges/block, 3125 blocks.
__global__ __launch_bounds__(256) void edge_kernel(
    const float*  __restrict__ x,
    const int*    __restrict__ ei,
    const float*  __restrict__ ea,
    const float*  __restrict__ b1,
    const __bf16* __restrict__ w2p,
    const __bf16* __restrict__ w1p,
    const __bf16* __restrict__ b2p,
    float* __restrict__ outp, int copyMask)
{
    __shared__ __bf16 hT[4][128][32];    // 32 KB, wave-private slices
    __shared__ __bf16 w2c[8 * 2 * 512];  // 16 KB K-chunk of packed w2

    const int t    = threadIdx.x;
    const int w    = t >> 6;
    const int lane = t & 63;
    const int l    = lane & 31;
    const int half = lane >> 5;
    const int eb   = blockIdx.x * 128 + w * 32;
    const int e    = eb + l;

    float* __restrict__ myout = outp + (size_t)(blockIdx.x & copyMask) * 800000;

    // ---- phase 1: hT[w][c][e] = relu(ea@w1+b1) via 8 MFMAs, wave-private ----
    {
        union { bf16x8 v; __hip_bfloat162 h2[4]; } eaf[2];
#pragma unroll
        for (int kk = 0; kk < 2; ++kk) {
            float4 a0 = *(const float4*)(ea + e * 32 + kk * 16 + half * 8);
            float4 a1 = *(const float4*)(ea + e * 32 + kk * 16 + half * 8 + 4);
            eaf[kk].h2[0] = __float22bfloat162_rn(make_float2(a0.x, a0.y));
            eaf[kk].h2[1] = __float22bfloat162_rn(make_float2(a0.z, a0.w));
            eaf[kk].h2[2] = __float22bfloat162_rn(make_float2(a1.x, a1.y));
            eaf[kk].h2[3] = __float22bfloat162_rn(make_float2(a1.z, a1.w));
        }
#pragma unroll
        for (int r = 0; r < 4; ++r) {
            bf16x8 w1f0 = *(const bf16x8*)(w1p + ((r * 2 + 0) * 64 + lane) * 8);
            bf16x8 w1f1 = *(const bf16x8*)(w1p + ((r * 2 + 1) * 64 + lane) * 8);
            f32x16 hacc;
#pragma unroll
            for (int i = 0; i < 16; ++i) hacc[i] = 0.f;
            hacc = __builtin_amdgcn_mfma_f32_32x32x16_bf16(w1f0, eaf[0].v, hacc, 0, 0, 0);
            hacc = __builtin_amdgcn_mfma_f32_32x32x16_bf16(w1f1, eaf[1].v, hacc, 0, 0, 0);
#pragma unroll
            for (int i = 0; i < 16; ++i) {
                int row = (i & 3) + ((i >> 2) << 3) + (half << 2);   // verified C/D map
                int c   = r * 32 + row;
                hT[w][c][l] = (__bf16)fmaxf(hacc[i] + b1[c], 0.f);
            }
        }
    }

    // ---- gather xs = x[src[e]] : per-lane 16 floats at i = ih*16 + half*8 + j ----
    const int srcv = ei[e];
    float xsv[16];
#pragma unroll
    for (int ih = 0; ih < 2; ++ih) {
        float4 a0 = *(const float4*)(x + srcv * 32 + ih * 16 + half * 8);
        float4 a1 = *(const float4*)(x + srcv * 32 + ih * 16 + half * 8 + 4);
        xsv[ih * 8 + 0] = a0.x; xsv[ih * 8 + 1] = a0.y;
        xsv[ih * 8 + 2] = a0.z; xsv[ih * 8 + 3] = a0.w;
        xsv[ih * 8 + 4] = a1.x; xsv[ih * 8 + 5] = a1.y;
        xsv[ih * 8 + 6] = a1.z; xsv[ih * 8 + 7] = a1.w;
    }

    // ---- prefetch destination node ids (avoid tail-latency loads) ----
    int dstv[16];
#pragma unroll
    for (int i = 0; i < 16; ++i) {
        int el = (i & 3) + ((i >> 2) << 3) + (half << 2);
        dstv[i] = ei[EE + eb + el];
    }

    f32x16 acc;
#pragma unroll
    for (int i = 0; i < 16; ++i) acc[i] = 0.f;

    // ---- main K loop: 16 chunks x 8 c, register-prefetched w2 chunk staging ----
    const char* w2g = (const char*)w2p;
    float4 pf[4];
#pragma unroll
    for (int s = 0; s < 4; ++s)
        pf[s] = *(const float4*)(w2g + t * 16 + s * 4096);

    for (int cc = 0; cc < 16; ++cc) {
        __syncthreads();                      // prev chunk's compute done
#pragma unroll
        for (int s = 0; s < 4; ++s)
            ((float4*)w2c)[t + s * 256] = pf[s];
        __syncthreads();
        if (cc < 15) {
#pragma unroll
            for (int s = 0; s < 4; ++s)       // overlap next chunk load with compute
                pf[s] = *(const float4*)(w2g + (cc + 1) * 16384 + t * 16 + s * 4096);
        }
#pragma unroll
        for (int cl = 0; cl < 8; ++cl) {
            const int   c  = cc * 8 + cl;
            const float hv = (float)hT[w][c][l];
#pragma unroll
            for (int ih = 0; ih < 2; ++ih) {
                bf16x8 bfr = *(const bf16x8*)&w2c[(cl * 2 + ih) * 512 + lane * 8];
                union { bf16x8 v; __hip_bfloat162 h2[4]; } A;
#pragma unroll
                for (int jj = 0; jj < 4; ++jj) {
                    float2 p = make_float2(hv * xsv[ih * 8 + jj * 2],
                                           hv * xsv[ih * 8 + jj * 2 + 1]);
                    A.h2[jj] = __float22bfloat162_rn(p);   // v_cvt_pk_bf16_f32
                }
                acc = __builtin_amdgcn_mfma_f32_32x32x16_bf16(A.v, bfr, acc, 0, 0, 0);
            }
        }
    }

    // ---- b2 contribution: one extra K-step with h == 1 ----
#pragma unroll
    for (int ih = 0; ih < 2; ++ih) {
        bf16x8 bfr = *(const bf16x8*)(b2p + (ih * 64 + lane) * 8);
        union { bf16x8 v; __hip_bfloat162 h2[4]; } A;
#pragma unroll
        for (int jj = 0; jj < 4; ++jj) {
            float2 p = make_float2(xsv[ih * 8 + jj * 2], xsv[ih * 8 + jj * 2 + 1]);
            A.h2[jj] = __float22bfloat162_rn(p);
        }
        acc = __builtin_amdgcn_mfma_f32_32x32x16_bf16(A.v, bfr, acc, 0, 0, 0);
    }

    // ---- scatter into this block's replica (XCD-local L2 atomics) ----
#pragma unroll
    for (int i = 0; i < 16; ++i)
        atomicAdd(myout + dstv[i] * 32 + l, acc[i]);
}

extern "C" void kernel_launch(void* const* d_in, const int* in_sizes, int n_in,
                              void* d_out, int out_size, void* d_ws, size_t ws_size,
                              hipStream_t stream) {
    const float* x    = (const float*)d_in[0];
    const int*   ei   = (const int*)  d_in[1];
    const float* ea   = (const float*)d_in[2];
    const float* w1   = (const float*)d_in[3];
    const float* b1   = (const float*)d_in[4];
    const float* w2   = (const float*)d_in[5];
    const float* b2   = (const float*)d_in[6];
    const float* root = (const float*)d_in[7];
    const float* bias = (const float*)d_in[8];
    float* out = (float*)d_out;

    __bf16* w2p = (__bf16*)d_ws;                          // 262144 B
    __bf16* w1p = (__bf16*)((char*)d_ws + 262144);        //   8192 B
    __bf16* b2p = (__bf16*)((char*)d_ws + 270336);        //   2048 B
    const size_t partOff = 272384;
    const size_t one = 800000ull * sizeof(float);         // 3.2 MB per replica
    size_t avail = (ws_size > partOff) ? ws_size - partOff : 0;
    int nc = 0;
    for (int c = 8; c >= 1; c >>= 1)
        if ((size_t)c * one <= avail) { nc = c; break; }

    pack_kernel<<<532, 256, 0, stream>>>(w1, w2, b2, w2p, w1p, b2p);
    root_kernel<<<(NN * 32) / 256, 256, 0, stream>>>(x, root, bias, out);

    if (nc > 0) {
        float* part = (float*)((char*)d_ws + partOff);
        hipMemsetAsync(part, 0, (size_t)nc * one, stream);
        edge_kernel<<<EE / 128, 256, 0, stream>>>(x, ei, ea, b1, w2p, w1p, b2p,
                                                  part, nc - 1);
        reduce_kernel<<<(NN * 32) / 256, 256, 0, stream>>>(part, nc, out);
    } else {
        // ws too small for replicas: atomics straight into out (round-2 behavior)
        edge_kernel<<<EE / 128, 256, 0, stream>>>(x, ei, ea, b1, w2p, w1p, b2p,
                                                  out, 0);
    }
}

// Round 4
// 299.519 us; speedup vs baseline: 15.3146x; 1.3533x over previous
//
#include <hip/hip_runtime.h>
#include <hip/hip_bf16.h>

// NNConv on MI355X. msg[E x 32] = Z[E x 4096] @ w2r[4096 x 32],
// Z[e, c*32+i] = h[e,c]*xs[e,i] generated on the fly in A-fragments.
// Round 4: 64 edges/wave (2 edge-groups, B-fragment reuse x2), double-buffered
// 16 KB w2 chunks (1 barrier / 32 MFMAs), phase-1 interleaved per 32-c slice
// (wave-private hT, 16 KB), fused prep (pack+zero) and final (root+reduce).

#define NN 25000
#define EE 400000

typedef __bf16 bf16x8 __attribute__((ext_vector_type(8)));
typedef float  f32x16 __attribute__((ext_vector_type(16)));

// ---------------- prep: pack w1/w2/b2 to fragment layout + zero replicas ----------------
__global__ __launch_bounds__(256) void prep_kernel(
    const float* __restrict__ w1, const float* __restrict__ w2,
    const float* __restrict__ b2,
    __bf16* __restrict__ w2p, __bf16* __restrict__ w1p, __bf16* __restrict__ b2p,
    float4* __restrict__ part4, int nzero4)
{
    int b = blockIdx.x;
    if (b < 532) {                       // 532*256 = 136192 pack threads, exact
        int t = b * 256 + threadIdx.x;
        if (t < 131072) {
            int j = t & 7, lane = (t >> 3) & 63, ih = (t >> 9) & 1, c = t >> 10;
            w2p[t] = (__bf16)w2[c * 1024 + (ih * 16 + ((lane >> 5) << 3) + j) * 32 + (lane & 31)];
        } else if (t < 135168) {
            int u = t - 131072;
            int j = u & 7, lane = (u >> 3) & 63, kk = (u >> 9) & 1, r = u >> 10;
            w1p[u] = (__bf16)w1[(kk * 16 + ((lane >> 5) << 3) + j) * 128 + r * 32 + (lane & 31)];
        } else {
            int u = t - 135168;
            int j = u & 7, lane = (u >> 3) & 63, ih = u >> 9;
            b2p[u] = (__bf16)b2[(ih * 16 + ((lane >> 5) << 3) + j) * 32 + (lane & 31)];
        }
    } else {
        int z = (b - 532) * 256 + threadIdx.x;
        if (z < nzero4) part4[z] = make_float4(0.f, 0.f, 0.f, 0.f);
    }
}

// ---------------- final: out = x@root + bias + sum(replicas) ----------------
__global__ __launch_bounds__(256) void final_kernel(
    const float* __restrict__ x, const float* __restrict__ root,
    const float* __restrict__ bias, const float* __restrict__ part,
    int ncopies, float* __restrict__ out)
{
    int gid = blockIdx.x * 256 + threadIdx.x;   // exactly NN*32
    int n = gid >> 5, o = gid & 31;
    float acc = bias[o];
    const float* xr = x + (n << 5);
#pragma unroll
    for (int i = 0; i < 32; ++i)
        acc = fmaf(xr[i], root[(i << 5) + o], acc);
    for (int c = 0; c < ncopies; ++c) acc += part[(size_t)c * 800000 + gid];
    out[gid] = acc;
}

// ---------------- fused MFMA edge kernel ----------------
// 256 thr = 4 waves x 64 edges = 256 edges/block, 1563 blocks (last partial).
__global__ __launch_bounds__(256, 3) void edge_kernel(
    const float*  __restrict__ x,
    const int*    __restrict__ ei,
    const float*  __restrict__ ea,
    const float*  __restrict__ b1,
    const __bf16* __restrict__ w2p,
    const __bf16* __restrict__ w1p,
    const __bf16* __restrict__ b2p,
    float* __restrict__ outp, int copyMask)
{
    __shared__ __align__(16) __bf16 w2c[2][8192];         // 2 x 16 KB dbuf (8 c/chunk)
    __shared__ unsigned int hTp[4][32][32];               // 16 KB: per-r slice, packed (eg0,eg1)
    __shared__ float b1L[128];

    const int t    = threadIdx.x;
    const int w    = t >> 6;
    const int lane = t & 63;
    const int l    = lane & 31;
    const int half = lane >> 5;

    const int  ebraw = blockIdx.x * 256 + w * 64;
    const bool live  = (ebraw + 64) <= EE;                // wave-uniform
    const int  ebw   = live ? ebraw : (EE - 64);

    float* __restrict__ myout = outp + (size_t)(blockIdx.x & copyMask) * 800000;

    if (t < 128) b1L[t] = b1[t];

    // ---- edge-attr fragments, 2 edge-groups ----
    union { bf16x8 v; __hip_bfloat162 h2[4]; } eaf[2][2];
#pragma unroll
    for (int eg = 0; eg < 2; ++eg)
#pragma unroll
        for (int kk = 0; kk < 2; ++kk) {
            const float* p = ea + (ebw + eg * 32 + l) * 32 + kk * 16 + half * 8;
            float4 a0 = *(const float4*)p;
            float4 a1 = *(const float4*)(p + 4);
            eaf[eg][kk].h2[0] = __float22bfloat162_rn(make_float2(a0.x, a0.y));
            eaf[eg][kk].h2[1] = __float22bfloat162_rn(make_float2(a0.z, a0.w));
            eaf[eg][kk].h2[2] = __float22bfloat162_rn(make_float2(a1.x, a1.y));
            eaf[eg][kk].h2[3] = __float22bfloat162_rn(make_float2(a1.z, a1.w));
        }

    // ---- gather xs rows for both edge-groups ----
    float xs0[16], xs1[16];
    {
        int s0 = ei[ebw + l], s1 = ei[ebw + 32 + l];
#pragma unroll
        for (int ih = 0; ih < 2; ++ih) {
            float4 a0 = *(const float4*)(x + s0 * 32 + ih * 16 + half * 8);
            float4 a1 = *(const float4*)(x + s0 * 32 + ih * 16 + half * 8 + 4);
            xs0[ih*8+0]=a0.x; xs0[ih*8+1]=a0.y; xs0[ih*8+2]=a0.z; xs0[ih*8+3]=a0.w;
            xs0[ih*8+4]=a1.x; xs0[ih*8+5]=a1.y; xs0[ih*8+6]=a1.z; xs0[ih*8+7]=a1.w;
            float4 b0 = *(const float4*)(x + s1 * 32 + ih * 16 + half * 8);
            float4 b1v= *(const float4*)(x + s1 * 32 + ih * 16 + half * 8 + 4);
            xs1[ih*8+0]=b0.x; xs1[ih*8+1]=b0.y; xs1[ih*8+2]=b0.z; xs1[ih*8+3]=b0.w;
            xs1[ih*8+4]=b1v.x; xs1[ih*8+5]=b1v.y; xs1[ih*8+6]=b1v.z; xs1[ih*8+7]=b1v.w;
        }
    }

    f32x16 acc0, acc1;
#pragma unroll
    for (int i = 0; i < 16; ++i) { acc0[i] = 0.f; acc1[i] = 0.f; }

    // ---- w2 chunk pipeline prologue: chunk0 -> buf0, pf holds chunk1 ----
    const char* w2g = (const char*)w2p;
    float4 pf[4];
#pragma unroll
    for (int s = 0; s < 4; ++s)
        pf[s] = *(const float4*)(w2g + s * 4096 + t * 16);
#pragma unroll
    for (int s = 0; s < 4; ++s)
        ((float4*)w2c[0])[t + s * 256] = pf[s];
#pragma unroll
    for (int s = 0; s < 4; ++s)
        pf[s] = *(const float4*)(w2g + 16384 + s * 4096 + t * 16);
    __syncthreads();

    // chunk body: write pf(chunk cc+1)->WB, issue pf loads (cc+2), compute RB, barrier
    auto chunk = [&](int cc, const __bf16* RB, __bf16* WBp) {
        if (cc < 15) {
            float4* WB = (float4*)WBp;
#pragma unroll
            for (int s = 0; s < 4; ++s) WB[t + s * 256] = pf[s];
        }
        if (cc < 14) {
#pragma unroll
            for (int s = 0; s < 4; ++s)
                pf[s] = *(const float4*)(w2g + (cc + 2) * 16384 + s * 4096 + t * 16);
        }
#pragma unroll
        for (int cl = 0; cl < 8; ++cl) {
            unsigned int u = hTp[w][((cc & 3) << 3) + cl][l];
            float hv0 = __uint_as_float(u << 16);
            float hv1 = __uint_as_float(u & 0xffff0000u);
#pragma unroll
            for (int ih = 0; ih < 2; ++ih) {
                bf16x8 bfr = *(const bf16x8*)(RB + (((cl << 1) + ih) * 64 + lane) * 8);
                union { bf16x8 v; __hip_bfloat162 h2[4]; } A;
#pragma unroll
                for (int p = 0; p < 4; ++p)
                    A.h2[p] = __float22bfloat162_rn(make_float2(hv0 * xs0[ih*8+2*p],
                                                                hv0 * xs0[ih*8+2*p+1]));
                acc0 = __builtin_amdgcn_mfma_f32_32x32x16_bf16(A.v, bfr, acc0, 0, 0, 0);
#pragma unroll
                for (int p = 0; p < 4; ++p)
                    A.h2[p] = __float22bfloat162_rn(make_float2(hv1 * xs1[ih*8+2*p],
                                                                hv1 * xs1[ih*8+2*p+1]));
                acc1 = __builtin_amdgcn_mfma_f32_32x32x16_bf16(A.v, bfr, acc1, 0, 0, 0);
            }
        }
        __syncthreads();
    };

    // ---- main loop: r-slices of 32 c, phase-1 interleaved (wave-private) ----
#pragma unroll 1
    for (int r = 0; r < 4; ++r) {
        // phase 1 slice: h[r*32 .. r*32+32) for both edge-groups
        {
            bf16x8 w1f0 = *(const bf16x8*)(w1p + ((r * 2 + 0) * 64 + lane) * 8);
            bf16x8 w1f1 = *(const bf16x8*)(w1p + ((r * 2 + 1) * 64 + lane) * 8);
            f32x16 h0, h1;
#pragma unroll
            for (int i = 0; i < 16; ++i) { h0[i] = 0.f; h1[i] = 0.f; }
            h0 = __builtin_amdgcn_mfma_f32_32x32x16_bf16(w1f0, eaf[0][0].v, h0, 0, 0, 0);
            h0 = __builtin_amdgcn_mfma_f32_32x32x16_bf16(w1f1, eaf[0][1].v, h0, 0, 0, 0);
            h1 = __builtin_amdgcn_mfma_f32_32x32x16_bf16(w1f0, eaf[1][0].v, h1, 0, 0, 0);
            h1 = __builtin_amdgcn_mfma_f32_32x32x16_bf16(w1f1, eaf[1][1].v, h1, 0, 0, 0);
#pragma unroll
            for (int i = 0; i < 16; ++i) {
                int row = (i & 3) + ((i >> 2) << 3) + (half << 2);
                float bb = b1L[r * 32 + row];
                float lo = fmaxf(h0[i] + bb, 0.f);
                float hi = fmaxf(h1[i] + bb, 0.f);
                __hip_bfloat162 pk = __float22bfloat162_rn(make_float2(lo, hi));
                hTp[w][row][l] = *(unsigned int*)&pk;
            }
        }
        chunk(r * 4 + 0, w2c[0], w2c[1]);
        chunk(r * 4 + 1, w2c[1], w2c[0]);
        chunk(r * 4 + 2, w2c[0], w2c[1]);
        chunk(r * 4 + 3, w2c[1], w2c[0]);
    }

    // ---- b2 contribution: one extra K-step with h == 1 ----
#pragma unroll
    for (int ih = 0; ih < 2; ++ih) {
        bf16x8 bfr = *(const bf16x8*)(b2p + (ih * 64 + lane) * 8);
        union { bf16x8 v; __hip_bfloat162 h2[4]; } A;
#pragma unroll
        for (int p = 0; p < 4; ++p)
            A.h2[p] = __float22bfloat162_rn(make_float2(xs0[ih*8+2*p], xs0[ih*8+2*p+1]));
        acc0 = __builtin_amdgcn_mfma_f32_32x32x16_bf16(A.v, bfr, acc0, 0, 0, 0);
#pragma unroll
        for (int p = 0; p < 4; ++p)
            A.h2[p] = __float22bfloat162_rn(make_float2(xs1[ih*8+2*p], xs1[ih*8+2*p+1]));
        acc1 = __builtin_amdgcn_mfma_f32_32x32x16_bf16(A.v, bfr, acc1, 0, 0, 0);
    }

    // ---- scatter (skip for clamped tail waves) ----
    if (live) {
#pragma unroll
        for (int i = 0; i < 16; ++i) {
            int el = (i & 3) + ((i >> 2) << 3) + (half << 2);
            int d0 = ei[EE + ebw + el];
            int d1 = ei[EE + ebw + 32 + el];
            atomicAdd(myout + d0 * 32 + l, acc0[i]);
            atomicAdd(myout + d1 * 32 + l, acc1[i]);
        }
    }
}

extern "C" void kernel_launch(void* const* d_in, const int* in_sizes, int n_in,
                              void* d_out, int out_size, void* d_ws, size_t ws_size,
                              hipStream_t stream) {
    const float* x    = (const float*)d_in[0];
    const int*   ei   = (const int*)  d_in[1];
    const float* ea   = (const float*)d_in[2];
    const float* w1   = (const float*)d_in[3];
    const float* b1   = (const float*)d_in[4];
    const float* w2   = (const float*)d_in[5];
    const float* b2   = (const float*)d_in[6];
    const float* root = (const float*)d_in[7];
    const float* bias = (const float*)d_in[8];
    float* out = (float*)d_out;

    __bf16* w2p = (__bf16*)d_ws;                          // 262144 B
    __bf16* w1p = (__bf16*)((char*)d_ws + 262144);        //   8192 B
    __bf16* b2p = (__bf16*)((char*)d_ws + 270336);        //   2048 B
    const size_t partOff = 272384;
    const size_t one = 800000ull * sizeof(float);         // 3.2 MB per replica
    size_t avail = (ws_size > partOff) ? ws_size - partOff : 0;
    int nc = 0;
    for (int c = 8; c >= 1; c >>= 1)
        if ((size_t)c * one <= avail) { nc = c; break; }

    float* part = (float*)((char*)d_ws + partOff);
    if (nc > 0) {
        int nzero4 = nc * 200000;                         // float4 count
        int zb = (nzero4 + 255) / 256;
        prep_kernel<<<532 + zb, 256, 0, stream>>>(w1, w2, b2, w2p, w1p, b2p,
                                                  (float4*)part, nzero4);
        edge_kernel<<<(EE + 255) / 256, 256, 0, stream>>>(x, ei, ea, b1, w2p, w1p, b2p,
                                                          part, nc - 1);
        final_kernel<<<(NN * 32) / 256, 256, 0, stream>>>(x, root, bias, part, nc, out);
    } else {
        // tiny-ws fallback: atomics straight into out (needs zeroed-then-root order)
        prep_kernel<<<532, 256, 0, stream>>>(w1, w2, b2, w2p, w1p, b2p, (float4*)part, 0);
        final_kernel<<<(NN * 32) / 256, 256, 0, stream>>>(x, root, bias, part, 0, out);
        edge_kernel<<<(EE + 255) / 256, 256, 0, stream>>>(x, ei, ea, b1, w2p, w1p, b2p,
                                                          out, 0);
    }
}